// Round 3
// baseline (36.800 us; speedup 1.0000x reference)
//
#include <hip/hip_runtime.h>

#define WINDOW 11
#define H 512
#define W 512
#define OH 502            // H - WINDOW + 1
#define OW 502
#define NCH 3
#define BATCH 8
#define RSTRIPE 16
#define NSTRIPES 32       // ceil(502/16)
#define NCOLBLK 2
#define STAGE 272         // staged columns per block (max 268), padded

#define NPIX_PER_BATCH (3.0f * 502.0f * 502.0f)   // 756012

// XOR swizzle on float4 index: bijective involution within each 64-entry
// group; spreads the 32B-stride lane pattern across LDS bank groups.
__device__ __forceinline__ int sw(int j) { return j ^ ((j >> 3) & 7); }

__device__ __forceinline__ float ssim_from(const float4& s) {
    const float n = 121.0f;
    const float inv_n = 1.0f / 121.0f;
    const float inv_nm1 = 1.0f / 120.0f;
    const float c1 = 1e-4f;   // (0.01)^2
    const float c2 = 9e-4f;   // (0.03)^2
    float mx  = s.x * inv_n;
    float my  = s.y * inv_n;
    float mxy = mx * my;
    float m2  = mx * mx + my * my;
    float cov = (s.w - n * mxy) * inv_nm1;   // covariance
    float v2  = (s.z - n * m2)  * inv_nm1;   // vx + vy
    return (2.f * mxy + c1) * (2.f * cov + c2) /
           ((m2 + c1) * (v2 + c2));
}

__global__ __launch_bounds__(256, 6) void ssim_main(const float* __restrict__ x,
                                                    const float* __restrict__ y,
                                                    float* __restrict__ partials) {
    __shared__ float4 V4[STAGE];   // per-column {sx, sy, sxx+syy, sxy}, swizzled
    __shared__ float red[4];

    const int blk  = blockIdx.x;             // (img*NSTRIPES + s)*2 + cblk
    const int cblk = blk & 1;
    const int rest = blk >> 1;
    const int s    = rest & (NSTRIPES - 1);
    const int img  = rest >> 5;              // b*NCH + c

    const int cb    = cblk ? 256 : 0;        // first staged input column
    const int ncols = cblk ? 256 : 268;      // staged columns
    const int ntap  = cblk ? 123 : 128;      // output-computing threads (span 2)
    const int ob    = cblk ? 256 : 0;        // first output column

    const float* __restrict__ xi = x + (size_t)img * H * W;
    const float* __restrict__ yi = y + (size_t)img * H * W;
    const int t  = threadIdx.x;
    const int i0 = s * RSTRIPE;
    const int i1 = min(i0 + RSTRIPE, OH);

    const bool slideActive = (2 * t < ncols);
    const bool tapActive   = (t < ntap);
    const int  c0 = cb + 2 * t;              // this thread's slide column pair

    // --- init: vertical column sums for rows i0..i0+10, kept in registers ---
    float4 v0 = make_float4(0.f, 0.f, 0.f, 0.f);
    float4 v1 = make_float4(0.f, 0.f, 0.f, 0.f);
    if (slideActive) {
        const float* xp = xi + (size_t)i0 * W + c0;
        const float* yp = yi + (size_t)i0 * W + c0;
#pragma unroll
        for (int r = 0; r < WINDOW; ++r) {
            float2 a = *(const float2*)(xp + r * W);
            float2 b = *(const float2*)(yp + r * W);
            v0.x += a.x; v0.y += b.x; v0.z += a.x * a.x + b.x * b.x; v0.w += a.x * b.x;
            v1.x += a.y; v1.y += b.y; v1.z += a.y * a.y + b.y * b.y; v1.w += a.y * b.y;
        }
        V4[sw(2 * t)]     = v0;
        V4[sw(2 * t + 1)] = v1;
    }

    // --- precompute swizzled tap pointers (constant-indexed after unroll) ---
    const float4* ap[12];
#pragma unroll
    for (int k = 0; k < 12; ++k) ap[k] = &V4[sw(2 * t + k)];
    (void)ob;

    float acc = 0.f;
    for (int i = i0; i < i1; ++i) {
        __syncthreads();   // V4 for row i visible

        const bool more = (i + 1 < i1);
        float2 xo, yo, xn, yn;
        if (more && slideActive) {   // prefetch: consumed only after 2nd barrier
            xo = *(const float2*)(xi + (size_t)i * W + c0);
            yo = *(const float2*)(yi + (size_t)i * W + c0);
            xn = *(const float2*)(xi + (size_t)(i + WINDOW) * W + c0);
            yn = *(const float2*)(yi + (size_t)(i + WINDOW) * W + c0);
        }

        if (tapActive) {
            // 11-tap horizontal sum for first col, slide +1 tap for second
            float4 t0  = *ap[0];
            float4 sum = t0;
#pragma unroll
            for (int k = 1; k < WINDOW; ++k) {
                float4 v = *ap[k];
                sum.x += v.x; sum.y += v.y; sum.z += v.z; sum.w += v.w;
            }
            acc += ssim_from(sum);
            float4 t11 = *ap[11];
            sum.x += t11.x - t0.x;
            sum.y += t11.y - t0.y;
            sum.z += t11.z - t0.z;
            sum.w += t11.w - t0.w;
            acc += ssim_from(sum);
        }

        __syncthreads();   // all tap reads done before mutating V4

        if (more && slideActive) {
            // slide: remove input row i, add input row i+11 (register update)
            v0.x += xn.x - xo.x;
            v0.y += yn.x - yo.x;
            v0.z += xn.x * xn.x + yn.x * yn.x - xo.x * xo.x - yo.x * yo.x;
            v0.w += xn.x * yn.x - xo.x * yo.x;
            v1.x += xn.y - xo.y;
            v1.y += yn.y - yo.y;
            v1.z += xn.y * xn.y + yn.y * yn.y - xo.y * xo.y - yo.y * yo.y;
            v1.w += xn.y * yn.y - xo.y * yo.y;
            V4[sw(2 * t)]     = v0;
            V4[sw(2 * t + 1)] = v1;
        }
    }

    // --- block reduction (fixed order, deterministic) ---
    for (int off = 32; off > 0; off >>= 1)
        acc += __shfl_down(acc, off, 64);
    int wid = t >> 6, lane = t & 63;
    if (lane == 0) red[wid] = acc;
    __syncthreads();
    if (t == 0)
        partials[blk] = (red[0] + red[1]) + (red[2] + red[3]);
}

__global__ __launch_bounds__(256) void ssim_reduce(const float* __restrict__ partials,
                                                   float* __restrict__ out) {
    const int b = blockIdx.x;                      // one block per batch element
    const int t = threadIdx.x;
    const int per = NCH * NSTRIPES * NCOLBLK;      // 192 partials per batch
    float s = 0.f;
    for (int k = t; k < per; k += 256)
        s += partials[b * per + k];
    for (int off = 32; off > 0; off >>= 1)
        s += __shfl_down(s, off, 64);
    __shared__ float red[4];
    int wid = t >> 6, lane = t & 63;
    if (lane == 0) red[wid] = s;
    __syncthreads();
    if (t == 0) {
        float tot = (red[0] + red[1]) + (red[2] + red[3]);
        out[b] = (1.0f - tot / NPIX_PER_BATCH) * 0.5f;
    }
}

extern "C" void kernel_launch(void* const* d_in, const int* in_sizes, int n_in,
                              void* d_out, int out_size, void* d_ws, size_t ws_size,
                              hipStream_t stream) {
    const float* x = (const float*)d_in[0];
    const float* y = (const float*)d_in[1];
    float* out      = (float*)d_out;
    float* partials = (float*)d_ws;   // 1536 floats, fully overwritten each call

    const int nblocks = BATCH * NCH * NSTRIPES * NCOLBLK;   // 1536
    ssim_main<<<nblocks, 256, 0, stream>>>(x, y, partials);
    ssim_reduce<<<BATCH, 256, 0, stream>>>(partials, out);
}

// Round 4
// 33.279 us; speedup vs baseline: 1.1058x; 1.1058x over previous
//
#include <hip/hip_runtime.h>

#define WINDOW 11
#define H 512
#define W 512
#define OH 502            // H - WINDOW + 1
#define OW 502
#define NCH 3
#define BATCH 8
#define RSTRIPE 16
#define NSTRIPES 32       // ceil(502/16); last stripe has 6 rows
#define NGRP 5            // col groups: 4 x 118 outputs + 1 x 30
#define GRPW 118          // output cols per full group (64 lanes * 2 - 10 halo)
#define WAVES_PER_IMG (NSTRIPES * NGRP)                 // 160
#define NBLOCKS (BATCH * NCH * WAVES_PER_IMG / 4)       // 960

#define NPIX_PER_BATCH (3.0f * 502.0f * 502.0f)   // 756012

// XOR swizzle on local float4 index (0..127): bits0-2 ^= bits3-5. Bijective,
// spreads the 32B-stride tap pattern across LDS bank groups.
__device__ __forceinline__ int sw(int j) { return j ^ ((j >> 3) & 7); }

__device__ __forceinline__ float ssim_from(const float4& s) {
    const float n = 121.0f;
    const float inv_n = 1.0f / 121.0f;
    const float inv_nm1 = 1.0f / 120.0f;
    const float c1 = 1e-4f;   // (0.01)^2
    const float c2 = 9e-4f;   // (0.03)^2
    float mx  = s.x * inv_n;
    float my  = s.y * inv_n;
    float mxy = mx * my;
    float m2  = mx * mx + my * my;
    float cov = (s.w - n * mxy) * inv_nm1;   // covariance
    float v2  = (s.z - n * m2)  * inv_nm1;   // vx + vy
    float num = (2.f * mxy + c1) * (2.f * cov + c2);
    float den = (m2 + c1) * (v2 + c2);
    return num * __builtin_amdgcn_rcpf(den);  // den >= 9e-8, rel err ~1e-7
}

__global__ __launch_bounds__(256) void ssim_main(const float* __restrict__ x,
                                                 const float* __restrict__ y,
                                                 float* __restrict__ partials) {
    __shared__ float4 V4[4 * 128];   // 2 KB per wave, wave-private regions
    __shared__ float red[4];

    const int t    = threadIdx.x;
    const int widx = t >> 6;
    const int lane = t & 63;
    const int w    = blockIdx.x * 4 + widx;    // global wave id

    const int grp = w % NGRP;
    const int rs  = (w / NGRP) % NSTRIPES;
    const int img = w / WAVES_PER_IMG;         // b*NCH + c

    const int i0 = rs * RSTRIPE;
    const int i1 = min(i0 + RSTRIPE, OH);
    const int cstart = grp * GRPW;             // first staged/output col
    const int stagew = min(128, W - cstart);   // 128 (g<4) or 40 (g=4)
    const int outw   = min(GRPW, OW - cstart); // 118 or 30

    float4* Vw = V4 + widx * 128;              // this wave's LDS region
    const float* __restrict__ xi = x + (size_t)img * H * W;
    const float* __restrict__ yi = y + (size_t)img * H * W;

    const int  c0 = cstart + 2 * lane;               // this lane's column pair
    const bool slideActive = (2 * lane + 1 < stagew);
    const bool tapActive   = (2 * lane < outw);      // taps 2l..2l+11 <= stagew-1

    // --- init: vertical column sums for rows i0..i0+10, kept in registers ---
    float4 v0 = make_float4(0.f, 0.f, 0.f, 0.f);
    float4 v1 = make_float4(0.f, 0.f, 0.f, 0.f);
    if (slideActive) {
        const float* xp = xi + (size_t)i0 * W + c0;
        const float* yp = yi + (size_t)i0 * W + c0;
#pragma unroll
        for (int r = 0; r < WINDOW; ++r) {
            float2 a = *(const float2*)(xp + r * W);
            float2 b = *(const float2*)(yp + r * W);
            v0.x += a.x; v0.y += b.x; v0.z += a.x * a.x + b.x * b.x; v0.w += a.x * b.x;
            v1.x += a.y; v1.y += b.y; v1.z += a.y * a.y + b.y * b.y; v1.w += a.y * b.y;
        }
        Vw[sw(2 * lane)]     = v0;
        Vw[sw(2 * lane + 1)] = v1;
    }

    // --- precompute 12 swizzled tap pointers (static after unroll) ---
    const float4* ap[12];
#pragma unroll
    for (int k = 0; k < 12; ++k) ap[k] = &Vw[sw(2 * lane + k)];

    float acc = 0.f;
    // NO barriers in this loop: each wave's LDS region is private, and
    // within a wave DS ops execute in order (read-taps precede next writes).
    for (int i = i0; i < i1; ++i) {
        const bool more = (i + 1 < i1);
        float2 xo, yo, xn, yn;
        if (more & slideActive) {    // issue early; consumed after taps
            xo = *(const float2*)(xi + (size_t)i * W + c0);
            yo = *(const float2*)(yi + (size_t)i * W + c0);
            xn = *(const float2*)(xi + (size_t)(i + WINDOW) * W + c0);
            yn = *(const float2*)(yi + (size_t)(i + WINDOW) * W + c0);
        }

        if (tapActive) {
            float4 t0  = *ap[0];
            float4 sum = t0;
#pragma unroll
            for (int k = 1; k < WINDOW; ++k) {
                float4 v = *ap[k];
                sum.x += v.x; sum.y += v.y; sum.z += v.z; sum.w += v.w;
            }
            acc += ssim_from(sum);
            float4 t11 = *ap[11];
            sum.x += t11.x - t0.x;
            sum.y += t11.y - t0.y;
            sum.z += t11.z - t0.z;
            sum.w += t11.w - t0.w;
            acc += ssim_from(sum);
        }

        if (more & slideActive) {
            // slide: remove input row i, add input row i+11 (register update)
            v0.x += xn.x - xo.x;
            v0.y += yn.x - yo.x;
            v0.z += xn.x * xn.x + yn.x * yn.x - xo.x * xo.x - yo.x * yo.x;
            v0.w += xn.x * yn.x - xo.x * yo.x;
            v1.x += xn.y - xo.y;
            v1.y += yn.y - yo.y;
            v1.z += xn.y * xn.y + yn.y * yn.y - xo.y * xo.y - yo.y * yo.y;
            v1.w += xn.y * yn.y - xo.y * yo.y;
            Vw[sw(2 * lane)]     = v0;
            Vw[sw(2 * lane + 1)] = v1;
        }
    }

    // --- per-wave then per-block reduction (fixed order, deterministic) ---
    for (int off = 32; off > 0; off >>= 1)
        acc += __shfl_down(acc, off, 64);
    if (lane == 0) red[widx] = acc;
    __syncthreads();
    if (t == 0)
        partials[blockIdx.x] = (red[0] + red[1]) + (red[2] + red[3]);
}

__global__ __launch_bounds__(256) void ssim_reduce(const float* __restrict__ partials,
                                                   float* __restrict__ out) {
    const int b = blockIdx.x;          // one block per batch element
    const int t = threadIdx.x;
    const int per = NBLOCKS / BATCH;   // 120 contiguous block-partials per batch
    float s = 0.f;
    for (int k = t; k < per; k += 256)
        s += partials[b * per + k];
    for (int off = 32; off > 0; off >>= 1)
        s += __shfl_down(s, off, 64);
    __shared__ float red[4];
    int wid = t >> 6, lane = t & 63;
    if (lane == 0) red[wid] = s;
    __syncthreads();
    if (t == 0) {
        float tot = (red[0] + red[1]) + (red[2] + red[3]);
        out[b] = (1.0f - tot / NPIX_PER_BATCH) * 0.5f;
    }
}

extern "C" void kernel_launch(void* const* d_in, const int* in_sizes, int n_in,
                              void* d_out, int out_size, void* d_ws, size_t ws_size,
                              hipStream_t stream) {
    const float* x = (const float*)d_in[0];
    const float* y = (const float*)d_in[1];
    float* out      = (float*)d_out;
    float* partials = (float*)d_ws;   // 960 floats, fully overwritten each call

    ssim_main<<<NBLOCKS, 256, 0, stream>>>(x, y, partials);
    ssim_reduce<<<BATCH, 256, 0, stream>>>(partials, out);
}

// Round 5
// 32.481 us; speedup vs baseline: 1.1330x; 1.0246x over previous
//
#include <hip/hip_runtime.h>

#define WINDOW 11
#define H 512
#define W 512
#define OH 502            // H - WINDOW + 1
#define OW 502
#define NCH 3
#define BATCH 8
#define RSTRIPE 16
#define NSTRIPES 32       // ceil(502/16); last stripe has 6 rows
#define NGRP 5            // col groups: 4 x 118 outputs + 1 x 30
#define GRPW 118          // output cols per full group (64 lanes * 2 - 10 halo)
#define WAVES_PER_IMG (NSTRIPES * NGRP)                 // 160
#define NBLOCKS (BATCH * NCH * WAVES_PER_IMG / 4)       // 960

#define NPIX_PER_BATCH (3.0f * 502.0f * 502.0f)   // 756012

// ---- gfx9 DPP inclusive wave scan (64 lanes), VALU-pipe only ----
template <int CTRL, int RM>
__device__ __forceinline__ float scan_step(float x) {
    int s = __builtin_amdgcn_update_dpp(0, __builtin_bit_cast(int, x),
                                        CTRL, RM, 0xf, false);
    return x + __builtin_bit_cast(float, s);
}
__device__ __forceinline__ float wave_iscan(float x) {
    x = scan_step<0x111, 0xf>(x);   // row_shr:1
    x = scan_step<0x112, 0xf>(x);   // row_shr:2
    x = scan_step<0x114, 0xf>(x);   // row_shr:4
    x = scan_step<0x118, 0xf>(x);   // row_shr:8
    x = scan_step<0x142, 0xa>(x);   // row_bcast:15 -> rows 1,3
    x = scan_step<0x143, 0xc>(x);   // row_bcast:31 -> rows 2,3
    return x;
}

__device__ __forceinline__ float ssim_from(float sx, float sy, float s2, float sxy) {
    const float n = 121.0f;
    const float inv_n = 1.0f / 121.0f;
    const float inv_nm1 = 1.0f / 120.0f;
    const float c1 = 1e-4f;   // (0.01)^2
    const float c2 = 9e-4f;   // (0.03)^2
    float mx  = sx * inv_n;
    float my  = sy * inv_n;
    float mxy = mx * my;
    float m2  = mx * mx + my * my;
    float cov = (sxy - n * mxy) * inv_nm1;   // covariance
    float v2  = (s2  - n * m2)  * inv_nm1;   // vx + vy
    float num = (2.f * mxy + c1) * (2.f * cov + c2);
    float den = (m2 + c1) * (v2 + c2);
    return num * __builtin_amdgcn_rcpf(den);  // den >= 9e-8, rel err ~1e-7
}

__global__ __launch_bounds__(256) void ssim_main(const float* __restrict__ x,
                                                 const float* __restrict__ y,
                                                 float* __restrict__ partials) {
    __shared__ float red[4];

    const int t    = threadIdx.x;
    const int widx = t >> 6;
    const int lane = t & 63;
    const int w    = blockIdx.x * 4 + widx;    // global wave id

    const int grp = w % NGRP;
    const int rs  = (w / NGRP) % NSTRIPES;
    const int img = w / WAVES_PER_IMG;         // b*NCH + c

    const int i0 = rs * RSTRIPE;
    const int i1 = min(i0 + RSTRIPE, OH);
    const int cstart = grp * GRPW;             // first staged/output col
    const int stagew = min(128, W - cstart);   // 128 (g<4) or 40 (g=4)
    const int outw   = min(GRPW, OW - cstart); // 118 or 30

    const float* __restrict__ xi = x + (size_t)img * H * W;
    const float* __restrict__ yi = y + (size_t)img * H * W;

    const int  c0 = cstart + 2 * lane;               // this lane's column pair
    const bool slideActive = (2 * lane + 1 < stagew);
    const bool tapActive   = (2 * lane < outw);

    // --- init: vertical column sums for rows i0..i0+10, in registers ---
    float4 v0 = make_float4(0.f, 0.f, 0.f, 0.f);
    float4 v1 = make_float4(0.f, 0.f, 0.f, 0.f);
    if (slideActive) {
        const float* xp = xi + (size_t)i0 * W + c0;
        const float* yp = yi + (size_t)i0 * W + c0;
#pragma unroll
        for (int r = 0; r < WINDOW; ++r) {
            float2 a = *(const float2*)(xp + r * W);
            float2 b = *(const float2*)(yp + r * W);
            v0.x += a.x; v0.y += b.x; v0.z += a.x * a.x + b.x * b.x; v0.w += a.x * b.x;
            v1.x += a.y; v1.y += b.y; v1.z += a.y * a.y + b.y * b.y; v1.w += a.y * b.y;
        }
    }

    float acc = 0.f;
    for (int i = i0; i < i1; ++i) {
        const bool more = (i + 1 < i1);
        float2 xo, yo, xn, yn;
        if (more & slideActive) {    // issue early; consumed after the scan
            xo = *(const float2*)(xi + (size_t)i * W + c0);
            yo = *(const float2*)(yi + (size_t)i * W + c0);
            xn = *(const float2*)(xi + (size_t)(i + WINDOW) * W + c0);
            yn = *(const float2*)(yi + (size_t)(i + WINDOW) * W + c0);
        }

        // ---- horizontal window sums via scan (all 64 lanes participate) ----
        // T = pairwise col total, S = inclusive prefix over lane pairs
        float Tx = v0.x + v1.x, Ty = v0.y + v1.y;
        float Tz = v0.z + v1.z, Tw = v0.w + v1.w;
        float Sx = wave_iscan(Tx), Sy = wave_iscan(Ty);
        float Sz = wave_iscan(Tz), Sw = wave_iscan(Tw);
        // fetch S and v1 from lane+5 (wraps for inactive tail lanes; masked)
        int src = lane + 5;
        float Ax = __shfl(Sx, src, 64), Ay = __shfl(Sy, src, 64);
        float Az = __shfl(Sz, src, 64), Aw = __shfl(Sw, src, 64);
        float Bx = __shfl(v1.x, src, 64), By = __shfl(v1.y, src, 64);
        float Bz = __shfl(v1.z, src, 64), Bw = __shfl(v1.w, src, 64);

        if (tapActive) {
            // W[2l]   = (S[l+5]-v1[l+5]) - (S[l]-T[l])   (P[2l+10]-P[2l-1])
            // W[2l+1] =  S[l+5] - S[l] + v1[l]           (P[2l+11]-P[2l])
            float ex = Ax - Bx - Sx + Tx;
            float ey = Ay - By - Sy + Ty;
            float ez = Az - Bz - Sz + Tz;
            float ew = Aw - Bw - Sw + Tw;
            acc += ssim_from(ex, ey, ez, ew);
            float ox = Ax - Sx + v1.x;
            float oy = Ay - Sy + v1.y;
            float oz = Az - Sz + v1.z;
            float ow = Aw - Sw + v1.w;
            acc += ssim_from(ox, oy, oz, ow);
        }

        if (more & slideActive) {
            // slide: remove input row i, add input row i+11 (register update)
            v0.x += xn.x - xo.x;
            v0.y += yn.x - yo.x;
            v0.z += xn.x * xn.x + yn.x * yn.x - xo.x * xo.x - yo.x * yo.x;
            v0.w += xn.x * yn.x - xo.x * yo.x;
            v1.x += xn.y - xo.y;
            v1.y += yn.y - yo.y;
            v1.z += xn.y * xn.y + yn.y * yn.y - xo.y * xo.y - yo.y * yo.y;
            v1.w += xn.y * yn.y - xo.y * yo.y;
        }
    }

    // --- per-wave then per-block reduction (fixed order, deterministic) ---
    for (int off = 32; off > 0; off >>= 1)
        acc += __shfl_down(acc, off, 64);
    if (lane == 0) red[widx] = acc;
    __syncthreads();
    if (t == 0)
        partials[blockIdx.x] = (red[0] + red[1]) + (red[2] + red[3]);
}

__global__ __launch_bounds__(256) void ssim_reduce(const float* __restrict__ partials,
                                                   float* __restrict__ out) {
    const int b = blockIdx.x;          // one block per batch element
    const int t = threadIdx.x;
    const int per = NBLOCKS / BATCH;   // 120 contiguous block-partials per batch
    float s = 0.f;
    for (int k = t; k < per; k += 256)
        s += partials[b * per + k];
    for (int off = 32; off > 0; off >>= 1)
        s += __shfl_down(s, off, 64);
    __shared__ float red[4];
    int wid = t >> 6, lane = t & 63;
    if (lane == 0) red[wid] = s;
    __syncthreads();
    if (t == 0) {
        float tot = (red[0] + red[1]) + (red[2] + red[3]);
        out[b] = (1.0f - tot / NPIX_PER_BATCH) * 0.5f;
    }
}

extern "C" void kernel_launch(void* const* d_in, const int* in_sizes, int n_in,
                              void* d_out, int out_size, void* d_ws, size_t ws_size,
                              hipStream_t stream) {
    const float* x = (const float*)d_in[0];
    const float* y = (const float*)d_in[1];
    float* out      = (float*)d_out;
    float* partials = (float*)d_ws;   // 960 floats, fully overwritten each call

    ssim_main<<<NBLOCKS, 256, 0, stream>>>(x, y, partials);
    ssim_reduce<<<BATCH, 256, 0, stream>>>(partials, out);
}

// Round 6
// 29.391 us; speedup vs baseline: 1.2521x; 1.1051x over previous
//
#include <hip/hip_runtime.h>

#define WINDOW 11
#define H 512
#define W 512
#define OH 502            // H - WINDOW + 1
#define OW 502
#define NCH 3
#define BATCH 8
#define RSTRIPE 16
#define NSTRIPES 32       // ceil(502/16); last stripe has 6 rows
#define NGRP 5            // col groups: 4 x 118 outputs + 1 x 30
#define GRPW 118          // output cols per full group (64 lanes * 2 - 10 halo)
#define WAVES_PER_IMG (NSTRIPES * NGRP)                 // 160
#define NBLOCKS (BATCH * NCH * WAVES_PER_IMG / 4)       // 960

#define NPIX_PER_BATCH (3.0f * 502.0f * 502.0f)   // 756012

// ---- gfx9 DPP inclusive wave scan (64 lanes), VALU-pipe only ----
template <int CTRL, int RM>
__device__ __forceinline__ float scan_step(float x) {
    int s = __builtin_amdgcn_update_dpp(0, __builtin_bit_cast(int, x),
                                        CTRL, RM, 0xf, false);
    return x + __builtin_bit_cast(float, s);
}
__device__ __forceinline__ float wave_iscan(float x) {
    x = scan_step<0x111, 0xf>(x);   // row_shr:1
    x = scan_step<0x112, 0xf>(x);   // row_shr:2
    x = scan_step<0x114, 0xf>(x);   // row_shr:4
    x = scan_step<0x118, 0xf>(x);   // row_shr:8
    x = scan_step<0x142, 0xa>(x);   // row_bcast:15 -> rows 1,3
    x = scan_step<0x143, 0xc>(x);   // row_bcast:31 -> rows 2,3
    return x;
}

__device__ __forceinline__ float ssim_from(float sx, float sy, float s2, float sxy) {
    const float n = 121.0f;
    const float inv_n = 1.0f / 121.0f;
    const float inv_nm1 = 1.0f / 120.0f;
    const float c1 = 1e-4f;   // (0.01)^2
    const float c2 = 9e-4f;   // (0.03)^2
    float mx  = sx * inv_n;
    float my  = sy * inv_n;
    float mxy = mx * my;
    float m2  = mx * mx + my * my;
    float cov = (sxy - n * mxy) * inv_nm1;   // covariance
    float v2  = (s2  - n * m2)  * inv_nm1;   // vx + vy
    float num = (2.f * mxy + c1) * (2.f * cov + c2);
    float den = (m2 + c1) * (v2 + c2);
    return num * __builtin_amdgcn_rcpf(den);  // den >= 9e-8, rel err ~1e-7
}

__global__ __launch_bounds__(256) void ssim_main(const float* __restrict__ x,
                                                 const float* __restrict__ y,
                                                 float* __restrict__ partials) {
    __shared__ float red[4];

    const int t    = threadIdx.x;
    const int widx = t >> 6;
    const int lane = t & 63;
    const int w    = blockIdx.x * 4 + widx;    // global wave id

    const int grp = w % NGRP;
    const int rs  = (w / NGRP) % NSTRIPES;
    const int img = w / WAVES_PER_IMG;         // b*NCH + c

    const int i0 = rs * RSTRIPE;
    const int i1 = min(i0 + RSTRIPE, OH);      // i1-i0 = 16 or 6, always even
    const int cstart = grp * GRPW;             // first staged/output col
    const int outw   = min(GRPW, OW - cstart); // 118 or 30
    // clamped column pair: out-of-range lanes read real (unused) data
    const int c0 = min(cstart + 2 * lane, W - 2);
    const bool tapActive = (2 * lane < outw);

    const float* __restrict__ xi = x + (size_t)img * H * W;
    const float* __restrict__ yi = y + (size_t)img * H * W;
    const float* xc = xi + c0;                 // this lane's column base
    const float* yc = yi + c0;

    // --- init: vertical column sums for rows i0..i0+10, in registers ---
    float4 v0 = make_float4(0.f, 0.f, 0.f, 0.f);
    float4 v1 = make_float4(0.f, 0.f, 0.f, 0.f);
#pragma unroll
    for (int r = 0; r < WINDOW; ++r) {
        float2 a = *(const float2*)(xc + (size_t)(i0 + r) * W);
        float2 b = *(const float2*)(yc + (size_t)(i0 + r) * W);
        v0.x += a.x; v0.y += b.x; v0.z += a.x * a.x + b.x * b.x; v0.w += a.x * b.x;
        v1.x += a.y; v1.y += b.y; v1.z += a.y * a.y + b.y * b.y; v1.w += a.y * b.y;
    }

    // slide loads for iteration j: old row j, new row j+11 (row clamped; loads
    // whose results would be OOB are never consumed by live outputs)
#define LD(j, xo, yo, xn, yn) do {                                  \
        int rn_ = min((j) + WINDOW, H - 1);                          \
        xo = *(const float2*)(xc + (size_t)(j) * W);                 \
        yo = *(const float2*)(yc + (size_t)(j) * W);                 \
        xn = *(const float2*)(xc + (size_t)rn_ * W);                 \
        yn = *(const float2*)(yc + (size_t)rn_ * W);                 \
    } while (0)

#define SLIDE(xo, yo, xn, yn) do {                                   \
        v0.x += xn.x - xo.x;                                          \
        v0.y += yn.x - yo.x;                                          \
        v0.z += xn.x * xn.x + yn.x * yn.x - xo.x * xo.x - yo.x * yo.x;\
        v0.w += xn.x * yn.x - xo.x * yo.x;                            \
        v1.x += xn.y - xo.y;                                          \
        v1.y += yn.y - yo.y;                                          \
        v1.z += xn.y * xn.y + yn.y * yn.y - xo.y * xo.y - yo.y * yo.y;\
        v1.w += xn.y * yn.y - xo.y * yo.y;                            \
    } while (0)

    float acc = 0.f;

#define COMPUTE() do {                                                        \
        float Tx = v0.x + v1.x, Ty = v0.y + v1.y;                             \
        float Tz = v0.z + v1.z, Tw = v0.w + v1.w;                             \
        float Sx = wave_iscan(Tx), Sy = wave_iscan(Ty);                       \
        float Sz = wave_iscan(Tz), Sw = wave_iscan(Tw);                       \
        int src = lane + 5;                                                   \
        float Ax = __shfl(Sx, src, 64), Ay = __shfl(Sy, src, 64);             \
        float Az = __shfl(Sz, src, 64), Aw = __shfl(Sw, src, 64);             \
        float Bx = __shfl(v1.x, src, 64), By = __shfl(v1.y, src, 64);         \
        float Bz = __shfl(v1.z, src, 64), Bw = __shfl(v1.w, src, 64);         \
        if (tapActive) {                                                      \
            acc += ssim_from(Ax - Bx - Sx + Tx, Ay - By - Sy + Ty,            \
                             Az - Bz - Sz + Tz, Aw - Bw - Sw + Tw);           \
            acc += ssim_from(Ax - Sx + v1.x, Ay - Sy + v1.y,                  \
                             Az - Sz + v1.z, Aw - Sw + v1.w);                 \
        }                                                                     \
    } while (0)

    // --- software-pipelined main loop: loads stay ~2 iterations ahead ---
    float2 xoA, yoA, xnA, ynA, xoB, yoB, xnB, ynB;
    LD(i0,     xoA, yoA, xnA, ynA);
    LD(i0 + 1, xoB, yoB, xnB, ynB);
    for (int i = i0; i < i1; i += 2) {
        COMPUTE();                       // row i
        SLIDE(xoA, yoA, xnA, ynA);       // -> window for row i+1
        LD(i + 2, xoA, yoA, xnA, ynA);   // prefetch iter i+2 (clamped)
        COMPUTE();                       // row i+1
        SLIDE(xoB, yoB, xnB, ynB);       // -> window for row i+2
        LD(i + 3, xoB, yoB, xnB, ynB);   // prefetch iter i+3 (clamped)
    }

    // --- per-wave then per-block reduction (fixed order, deterministic) ---
    for (int off = 32; off > 0; off >>= 1)
        acc += __shfl_down(acc, off, 64);
    if (lane == 0) red[widx] = acc;
    __syncthreads();
    if (t == 0)
        partials[blockIdx.x] = (red[0] + red[1]) + (red[2] + red[3]);
}

__global__ __launch_bounds__(256) void ssim_reduce(const float* __restrict__ partials,
                                                   float* __restrict__ out) {
    const int b = blockIdx.x;          // one block per batch element
    const int t = threadIdx.x;
    const int per = NBLOCKS / BATCH;   // 120 contiguous block-partials per batch
    float s = 0.f;
    for (int k = t; k < per; k += 256)
        s += partials[b * per + k];
    for (int off = 32; off > 0; off >>= 1)
        s += __shfl_down(s, off, 64);
    __shared__ float red[4];
    int wid = t >> 6, lane = t & 63;
    if (lane == 0) red[wid] = s;
    __syncthreads();
    if (t == 0) {
        float tot = (red[0] + red[1]) + (red[2] + red[3]);
        out[b] = (1.0f - tot / NPIX_PER_BATCH) * 0.5f;
    }
}

extern "C" void kernel_launch(void* const* d_in, const int* in_sizes, int n_in,
                              void* d_out, int out_size, void* d_ws, size_t ws_size,
                              hipStream_t stream) {
    const float* x = (const float*)d_in[0];
    const float* y = (const float*)d_in[1];
    float* out      = (float*)d_out;
    float* partials = (float*)d_ws;   // 960 floats, fully overwritten each call

    ssim_main<<<NBLOCKS, 256, 0, stream>>>(x, y, partials);
    ssim_reduce<<<BATCH, 256, 0, stream>>>(partials, out);
}